// Round 16
// baseline (180.393 us; speedup 1.0000x reference)
//
#include <hip/hip_runtime.h>
#include <hip/hip_bf16.h>

#define N_NODES 50000
#define N_EDGES 800000
#define IN_DIM 256
#define OUT_DIM 64
#define HEADS 4
#define HD 256          // HEADS*OUT_DIM
#define P_L 0.1f
#define TILE_N 64       // nodes per block in node kernel
#define CAP 64          // per-node edge bucket capacity (expected max deg ~43)
#define OVCAP 4096      // overflow list capacity
#define FILL_OFF 321    // prep blocks before fill region

typedef __attribute__((ext_vector_type(8))) short bf16x8;
typedef __attribute__((ext_vector_type(4))) float f32x4;

static __device__ __forceinline__ short f2bf(float f) {
    __hip_bfloat16 b = __float2bfloat16(f);
    return *(short*)&b;
}

// ---- prep+fill fused: weight conversion + fold + edge bucketing ----
// b<256: W_bt; b<320: W_obt2; b==320: fold; b>=321: fill (independent work)
__global__ __launch_bounds__(256) void prep_fill_kernel(
    const float* __restrict__ W_att, const float* __restrict__ b_att,
    const float* __restrict__ W_g,
    const float* __restrict__ W_in, const float* __restrict__ W_out,
    const int* __restrict__ src, const int* __restrict__ dst,
    short* __restrict__ W_bt, short* __restrict__ W_obt2,
    float* __restrict__ v_dst, float* __restrict__ v_src,
    float* __restrict__ c_dst, float* __restrict__ c_src,
    int* __restrict__ cursor, int* __restrict__ bucket_src,
    int* __restrict__ ov_list, int* __restrict__ ov_count) {
    int b = blockIdx.x, t = threadIdx.x;
    if (b >= FILL_OFF) {
        int e = (b - FILL_OFF) * 256 + t;
        if (e < N_EDGES) {
            int n = dst[e];
            int pos = atomicAdd(&cursor[n], 1);
            if (pos < CAP) {
                bucket_src[(size_t)n * CAP + pos] = src[e];
            } else {
                int oi = atomicAdd(ov_count, 1);
                if (oi < OVCAP) ov_list[oi] = e;
            }
        }
        return;
    }
    if (b < 256) {
        W_bt[t * 256 + b] = f2bf(W_in[b * 256 + t]);
    } else if (b < 320) {
        int flat = (b - 256) * 256 + t;        // [0, 16384)
        int k = flat & 63, oc = (flat >> 6) & 63, h = flat >> 12;
        W_obt2[flat] = f2bf(W_out[(h * 64 + k) * 64 + oc]);
    } else {
        int h = t >> 6, dd = t & 63;
        float sd = 0.f, ss = 0.f;
        for (int e = 0; e < 64; ++e) {
            float w = W_att[h * 4096 + dd * 64 + e];
            sd += w * W_g[h * 128 + e];
            ss += w * W_g[h * 128 + 64 + e];
        }
        v_dst[t] = sd;
        v_src[t] = ss;
        if (dd == 0) {
            float cd = 0.f, cs = 0.f;
            for (int e = 0; e < 64; ++e) {
                float bb = b_att[h * 64 + e];
                cd += bb * W_g[h * 128 + e];
                cs += bb * W_g[h * 128 + 64 + e];
            }
            c_dst[h] = cd;
            c_src[h] = cs;
        }
    }
}

// ---------------- node transform via MFMA, 8 waves/block ----------------
// 64 nodes/block, 512 threads. Wave (rp, hd): rows rp*32..+31, head hd.
// hh = relu(h@W_in+b); gd/gs per head; y = per-head hh@W_out.
__global__ __launch_bounds__(512) void node_mfma_kernel(
    const float* __restrict__ hin, const short* __restrict__ W_bt,
    const short* __restrict__ W_obt2, const float* __restrict__ b_in,
    const float* __restrict__ v_dst, const float* __restrict__ v_src,
    const float* __restrict__ c_dst, const float* __restrict__ c_src,
    __hip_bfloat16* __restrict__ y, float* __restrict__ gd,
    float* __restrict__ gs) {
    __shared__ short A_lds[TILE_N * 256];   // 32 KB, XOR-swizzled
    int t = threadIdx.x;
    int n0 = blockIdx.x * TILE_N;
    bool full = (n0 + TILE_N) <= N_NODES;

    // ---- stage h tile: 512 threads, 2 passes of 32 rows ----
    #pragma unroll
    for (int rr = 0; rr < 2; ++rr) {
        int r = rr * 32 + (t >> 4), c0 = (t & 15) * 16;
        int row = n0 + r;
        if (row > N_NODES - 1) row = N_NODES - 1;   // clamp (tail block)
        const float* hp = hin + (size_t)row * IN_DIM + c0;
        float fv[16];
        *(float4*)&fv[0]  = *(const float4*)(hp + 0);
        *(float4*)&fv[4]  = *(const float4*)(hp + 4);
        *(float4*)&fv[8]  = *(const float4*)(hp + 8);
        *(float4*)&fv[12] = *(const float4*)(hp + 12);
        short sv[16];
        #pragma unroll
        for (int j = 0; j < 16; ++j) sv[j] = f2bf(fv[j]);
        int swz = (r & 7) << 3;
        int base = r * 256 + c0;
        *(bf16x8*)&A_lds[(base + 0) ^ swz] = *(bf16x8*)&sv[0];
        *(bf16x8*)&A_lds[(base + 8) ^ swz] = *(bf16x8*)&sv[8];
    }
    __syncthreads();

    int l = t & 63, w8 = t >> 6;          // 8 waves
    int rp = w8 >> 2, hd = w8 & 3;        // row-pair, head
    int lr = l & 15, lg = l >> 4;
    int aswz = (lr & 7) << 3;

    f32x4 acc[2][4];   // [row-tile within pair][col-tile]
    #pragma unroll
    for (int i = 0; i < 2; ++i)
        #pragma unroll
        for (int ct = 0; ct < 4; ++ct) acc[i][ct] = (f32x4){0.f, 0.f, 0.f, 0.f};

    #pragma unroll
    for (int ks = 0; ks < 8; ++ks) {
        bf16x8 bfrag[4], afrag[2];
        #pragma unroll
        for (int ct = 0; ct < 4; ++ct)
            bfrag[ct] = *(const bf16x8*)(W_bt + (size_t)(hd * 64 + ct * 16 + lr) * 256 + ks * 32 + lg * 8);
        #pragma unroll
        for (int i = 0; i < 2; ++i)
            afrag[i] = *(bf16x8*)&A_lds[((rp * 32 + i * 16 + lr) * 256 + ks * 32 + lg * 8) ^ aswz];
        #pragma unroll
        for (int i = 0; i < 2; ++i)
            #pragma unroll
            for (int ct = 0; ct < 4; ++ct)
                acc[i][ct] = __builtin_amdgcn_mfma_f32_16x16x32_bf16(afrag[i], bfrag[ct], acc[i][ct], 0, 0, 0);
    }

    // ---- epilogue: relu(+b_in) in place, gd/gs partials ----
    int col[4];
    float vd[4], vs[4], bi[4];
    #pragma unroll
    for (int ct = 0; ct < 4; ++ct) {
        col[ct] = hd * 64 + ct * 16 + lr;
        bi[ct] = b_in[col[ct]];
        vd[ct] = v_dst[col[ct]];
        vs[ct] = v_src[col[ct]];
    }
    float pd[2][4], ps[2][4];   // [i][r]
    #pragma unroll
    for (int i = 0; i < 2; ++i)
        #pragma unroll
        for (int r = 0; r < 4; ++r) { pd[i][r] = 0.f; ps[i][r] = 0.f; }
    #pragma unroll
    for (int i = 0; i < 2; ++i)
        #pragma unroll
        for (int ct = 0; ct < 4; ++ct)
            #pragma unroll
            for (int r = 0; r < 4; ++r) {
                float v = fmaxf(acc[i][ct][r] + bi[ct], 0.f);
                acc[i][ct][r] = v;          // reuse as hh value
                pd[i][r] += v * vd[ct];
                ps[i][r] += v * vs[ct];
            }
    #pragma unroll
    for (int i = 0; i < 2; ++i)
        #pragma unroll
        for (int r = 0; r < 4; ++r) {
            #pragma unroll
            for (int off = 1; off < 16; off <<= 1) {
                pd[i][r] += __shfl_xor(pd[i][r], off, 64);
                ps[i][r] += __shfl_xor(ps[i][r], off, 64);
            }
        }
    if (lr == 0) {
        float cd = c_dst[hd], cs = c_src[hd];
        #pragma unroll
        for (int i = 0; i < 2; ++i)
            #pragma unroll
            for (int r = 0; r < 4; ++r) {
                int m = rp * 32 + i * 16 + lg * 4 + r;
                if (full || (n0 + m) < N_NODES) {
                    gd[(n0 + m) * HEADS + hd] = pd[i][r] + cd;
                    gs[(n0 + m) * HEADS + hd] = ps[i][r] + cs;
                }
            }
    }

    // ---- restage hh into A_lds for the y-GEMM ----
    __syncthreads();   // everyone done reading input-h tile
    #pragma unroll
    for (int i = 0; i < 2; ++i)
        #pragma unroll
        for (int ct = 0; ct < 4; ++ct)
            #pragma unroll
            for (int r = 0; r < 4; ++r) {
                int m = rp * 32 + i * 16 + lg * 4 + r;
                int idx = m * 256 + col[ct];
                A_lds[idx ^ ((m & 7) << 3)] = f2bf(acc[i][ct][r]);
            }
    __syncthreads();

    // ---- y-GEMM: wave (rp,hd): [32 nodes x 64k of head hd] @ W_out[hd] ----
    f32x4 acc2[2][4];
    #pragma unroll
    for (int i = 0; i < 2; ++i)
        #pragma unroll
        for (int ct = 0; ct < 4; ++ct) acc2[i][ct] = (f32x4){0.f, 0.f, 0.f, 0.f};
    #pragma unroll
    for (int ks = 0; ks < 2; ++ks) {
        bf16x8 bfrag[4], afrag[2];
        #pragma unroll
        for (int ct = 0; ct < 4; ++ct)
            bfrag[ct] = *(const bf16x8*)(W_obt2 + (size_t)(hd * 64 + ct * 16 + lr) * 64 + ks * 32 + lg * 8);
        #pragma unroll
        for (int i = 0; i < 2; ++i)
            afrag[i] = *(bf16x8*)&A_lds[((rp * 32 + i * 16 + lr) * 256 + hd * 64 + ks * 32 + lg * 8) ^ aswz];
        #pragma unroll
        for (int i = 0; i < 2; ++i)
            #pragma unroll
            for (int ct = 0; ct < 4; ++ct)
                acc2[i][ct] = __builtin_amdgcn_mfma_f32_16x16x32_bf16(afrag[i], bfrag[ct], acc2[i][ct], 0, 0, 0);
    }
    #pragma unroll
    for (int i = 0; i < 2; ++i)
        #pragma unroll
        for (int ct = 0; ct < 4; ++ct)
            #pragma unroll
            for (int r = 0; r < 4; ++r) {
                int m = rp * 32 + i * 16 + lg * 4 + r;
                if (full || (n0 + m) < N_NODES)
                    y[(size_t)(n0 + m) * HD + hd * 64 + ct * 16 + lr] =
                        __float2bfloat16(acc2[i][ct][r]);
            }
}

// -------- gather agg, barrier-free, 2 nodes/wave: out[n] = b_out + sum alpha*y
// lanes 0-31 -> node A, lanes 32-63 -> node B. Lane covers 8 cols (one uint4).
__global__ __launch_bounds__(256) void agg_kernel(
    const int* __restrict__ bucket_src, const int* __restrict__ cursor,
    const int* __restrict__ src, const int* __restrict__ dst,
    const int* __restrict__ ov_list, const int* __restrict__ ov_count,
    const float* __restrict__ dnorm, const float* __restrict__ b_g,
    const __hip_bfloat16* __restrict__ y, const float* __restrict__ gd,
    const float* __restrict__ gs, const float* __restrict__ b_out,
    float* __restrict__ out) {
    int t = threadIdx.x;
    int wv = t >> 6, lane = t & 63;
    int half = lane >> 5, sl = lane & 31;
    int n = blockIdx.x * 8 + wv * 2 + half;
    int head = sl >> 3;                       // flat col c = sl*8+j, head = c>>6
    int deg = cursor[n];
    if (deg > CAP) deg = CAP;
    float dn = dnorm[n];
    float gdh = gd[n * HEADS + head] + b_g[head];
    int degmax = max(deg, __shfl_xor(deg, 32, 64));   // other half's deg

    const uint4* yb = (const uint4*)y;        // row = 32 uint4
    const int* bp = bucket_src + (size_t)n * CAP;
    float a[8];
    #pragma unroll
    for (int j = 0; j < 8; ++j) a[j] = 0.f;

    for (int i = 0; i < degmax; i += 8) {
        // stage 1: 8 independent src-id broadcast loads
        int sarr[8];
        #pragma unroll
        for (int j = 0; j < 8; ++j) {
            int e = i + j;
            sarr[j] = (e < deg) ? bp[e] : -1;
        }
        // stage 2: dependent gathers, all independent of each other
        float gsv[8], dnv[8];
        uint4 v[8];
        #pragma unroll
        for (int j = 0; j < 8; ++j) {
            int s = sarr[j] < 0 ? 0 : sarr[j];
            gsv[j] = gs[s * HEADS + head];
            dnv[j] = dnorm[s];
            v[j] = yb[(size_t)s * 32 + sl];
        }
        // stage 3: math
        #pragma unroll
        for (int j = 0; j < 8; ++j) {
            float _h = gdh + gsv[j];
            float g = _h > 0.f ? _h : -P_L * _h;
            float al = (sarr[j] < 0) ? 0.f : g * dn * dnv[j];
            a[0] += __uint_as_float(v[j].x << 16) * al;
            a[1] += __uint_as_float(v[j].x & 0xffff0000u) * al;
            a[2] += __uint_as_float(v[j].y << 16) * al;
            a[3] += __uint_as_float(v[j].y & 0xffff0000u) * al;
            a[4] += __uint_as_float(v[j].z << 16) * al;
            a[5] += __uint_as_float(v[j].z & 0xffff0000u) * al;
            a[6] += __uint_as_float(v[j].w << 16) * al;
            a[7] += __uint_as_float(v[j].w & 0xffff0000u) * al;
        }
    }

    // overflow edges (cnt ~always 0; uniform branch, broadcast loads)
    int cnt = *ov_count;
    if (cnt > 0) {
        if (cnt > OVCAP) cnt = OVCAP;
        for (int j = 0; j < cnt; ++j) {
            int e = ov_list[j];
            if (dst[e] == n) {
                int s = src[e];
                float _h = gdh + gs[s * HEADS + head];
                float g = _h > 0.f ? _h : -P_L * _h;
                float al = g * dn * dnorm[s];
                uint4 vv = yb[(size_t)s * 32 + sl];
                a[0] += __uint_as_float(vv.x << 16) * al;
                a[1] += __uint_as_float(vv.x & 0xffff0000u) * al;
                a[2] += __uint_as_float(vv.y << 16) * al;
                a[3] += __uint_as_float(vv.y & 0xffff0000u) * al;
                a[4] += __uint_as_float(vv.z << 16) * al;
                a[5] += __uint_as_float(vv.z & 0xffff0000u) * al;
                a[6] += __uint_as_float(vv.w << 16) * al;
                a[7] += __uint_as_float(vv.w & 0xffff0000u) * al;
            }
        }
    }

    // reduce over heads: partners sl^8 (head bit0), sl^16 (head bit1); both <32
    #pragma unroll
    for (int j = 0; j < 8; ++j) {
        a[j] += __shfl_xor(a[j], 8, 64);
        a[j] += __shfl_xor(a[j], 16, 64);
    }
    // lanes sl<8 hold oc = sl*8+j
    if (sl < 8) {
        float4 b0 = *(const float4*)&b_out[sl * 8];
        float4 b1 = *(const float4*)&b_out[sl * 8 + 4];
        float4 o0, o1;
        o0.x = a[0] + b0.x; o0.y = a[1] + b0.y; o0.z = a[2] + b0.z; o0.w = a[3] + b0.w;
        o1.x = a[4] + b1.x; o1.y = a[5] + b1.y; o1.z = a[6] + b1.z; o1.w = a[7] + b1.w;
        *(float4*)&out[(size_t)n * OUT_DIM + sl * 8] = o0;
        *(float4*)&out[(size_t)n * OUT_DIM + sl * 8 + 4] = o1;
    }
}

extern "C" void kernel_launch(void* const* d_in, const int* in_sizes, int n_in,
                              void* d_out, int out_size, void* d_ws, size_t ws_size,
                              hipStream_t stream) {
    const float* h     = (const float*)d_in[0];
    const int*   src   = (const int*)d_in[1];
    const int*   dst   = (const int*)d_in[2];
    const float* dnorm = (const float*)d_in[3];
    const float* W_in  = (const float*)d_in[4];
    const float* b_in  = (const float*)d_in[5];
    const float* W_att = (const float*)d_in[6];
    const float* b_att = (const float*)d_in[7];
    const float* W_g   = (const float*)d_in[8];
    const float* b_g   = (const float*)d_in[9];
    const float* W_out = (const float*)d_in[10];
    const float* b_out = (const float*)d_in[11];
    float* out = (float*)d_out;

    char* ws = (char*)d_ws;
    __hip_bfloat16* y = (__hip_bfloat16*)ws;             // N*256 bf16 (25.6 MB)
    ws += (size_t)N_NODES * HD * sizeof(__hip_bfloat16);
    float* gd     = (float*)ws;  ws += (size_t)N_NODES * HEADS * sizeof(float);
    float* gs     = (float*)ws;  ws += (size_t)N_NODES * HEADS * sizeof(float);
    float* v_dst  = (float*)ws;  ws += 256 * sizeof(float);
    float* v_src  = (float*)ws;  ws += 256 * sizeof(float);
    float* c_dst  = (float*)ws;  ws += 16;
    float* c_src  = (float*)ws;  ws += 16;
    int* cursor     = (int*)ws;  ws += (size_t)N_NODES * sizeof(int);
    int* ov_count   = (int*)ws;  ws += 16;
    int* ov_list    = (int*)ws;  ws += OVCAP * sizeof(int);
    int* bucket_src = (int*)ws;  ws += (size_t)N_NODES * CAP * sizeof(int);
    short* W_bt     = (short*)ws; ws += 256 * 256 * sizeof(short);   // 128 KB
    short* W_obt2   = (short*)ws;                                    // 32 KB

    hipMemsetAsync(cursor, 0, (size_t)N_NODES * sizeof(int), stream);
    hipMemsetAsync(ov_count, 0, sizeof(int), stream);

    // prep (321 blocks) + fill (3125 blocks) in one launch
    prep_fill_kernel<<<FILL_OFF + (N_EDGES + 255) / 256, 256, 0, stream>>>(
        W_att, b_att, W_g, W_in, W_out, src, dst,
        W_bt, W_obt2, v_dst, v_src, c_dst, c_src,
        cursor, bucket_src, ov_list, ov_count);
    node_mfma_kernel<<<(N_NODES + TILE_N - 1) / TILE_N, 512, 0, stream>>>(
        h, W_bt, W_obt2, b_in, v_dst, v_src, c_dst, c_src, y, gd, gs);
    agg_kernel<<<N_NODES / 8, 256, 0, stream>>>(bucket_src, cursor, src, dst,
                                                ov_list, ov_count, dnorm, b_g,
                                                y, gd, gs, b_out, out);
}

// Round 17
// 167.429 us; speedup vs baseline: 1.0774x; 1.0774x over previous
//
#include <hip/hip_runtime.h>
#include <hip/hip_bf16.h>

#define N_NODES 50000
#define N_EDGES 800000
#define IN_DIM 256
#define OUT_DIM 64
#define HEADS 4
#define HD 256          // HEADS*OUT_DIM
#define P_L 0.1f
#define TILE_N 64       // nodes per block in node kernel
#define CAP 64          // per-node edge bucket capacity (expected max deg ~43)
#define OVCAP 4096      // overflow list capacity

typedef __attribute__((ext_vector_type(8))) short bf16x8;
typedef __attribute__((ext_vector_type(4))) float f32x4;

static __device__ __forceinline__ short f2bf(float f) {
    __hip_bfloat16 b = __float2bfloat16(f);
    return *(short*)&b;
}

// ---- prep: weight conversion + W_att fold + cursor/ov zeroing, one launch ----
// b<256: W_bt; b<320: W_obt2; b==320: fold; b>=321: zero cursor (+ov_count)
__global__ __launch_bounds__(256) void prep_kernel(
    const float* __restrict__ W_att, const float* __restrict__ b_att,
    const float* __restrict__ W_g,
    const float* __restrict__ W_in, const float* __restrict__ W_out,
    short* __restrict__ W_bt, short* __restrict__ W_obt2,
    float* __restrict__ v_dst, float* __restrict__ v_src,
    float* __restrict__ c_dst, float* __restrict__ c_src,
    int* __restrict__ cursor, int* __restrict__ ov_count) {
    int b = blockIdx.x, t = threadIdx.x;
    if (b < 256) {
        W_bt[t * 256 + b] = f2bf(W_in[b * 256 + t]);
    } else if (b < 320) {
        int flat = (b - 256) * 256 + t;        // [0, 16384)
        int k = flat & 63, oc = (flat >> 6) & 63, h = flat >> 12;
        W_obt2[flat] = f2bf(W_out[(h * 64 + k) * 64 + oc]);
    } else if (b == 320) {
        int h = t >> 6, dd = t & 63;
        float sd = 0.f, ss = 0.f;
        for (int e = 0; e < 64; ++e) {
            float w = W_att[h * 4096 + dd * 64 + e];
            sd += w * W_g[h * 128 + e];
            ss += w * W_g[h * 128 + 64 + e];
        }
        v_dst[t] = sd;
        v_src[t] = ss;
        if (dd == 0) {
            float cd = 0.f, cs = 0.f;
            for (int e = 0; e < 64; ++e) {
                float bb = b_att[h * 64 + e];
                cd += bb * W_g[h * 128 + e];
                cs += bb * W_g[h * 128 + 64 + e];
            }
            c_dst[h] = cd;
            c_src[h] = cs;
        }
    } else {
        int idx = (b - 321) * 256 + t;
        if (idx < N_NODES) cursor[idx] = 0;
        if (b == 321 && t == 0) *ov_count = 0;
    }
}

// ---------------- bucket fill: group SRC node ids by dst ----------------
__global__ __launch_bounds__(256) void fill_kernel(
    const int* __restrict__ src, const int* __restrict__ dst,
    int* __restrict__ cursor, int* __restrict__ bucket_src,
    int* __restrict__ ov_list, int* __restrict__ ov_count) {
    int e = blockIdx.x * 256 + threadIdx.x;
    if (e >= N_EDGES) return;
    int n = dst[e];
    int pos = atomicAdd(&cursor[n], 1);
    if (pos < CAP) {
        bucket_src[(size_t)n * CAP + pos] = src[e];
    } else {
        int oi = atomicAdd(ov_count, 1);
        if (oi < OVCAP) ov_list[oi] = e;
    }
}

// ---------------- node transform via MFMA (+ fused out-projection y) --------
// 64 nodes/block. hh = relu(h@W_in+b); gd/gs per head;
// y = (per-head hh@W_out) * dnorm[row]   <-- dnorm folded in so agg skips it
__global__ __launch_bounds__(256, 2) void node_mfma_kernel(
    const float* __restrict__ hin, const short* __restrict__ W_bt,
    const short* __restrict__ W_obt2, const float* __restrict__ b_in,
    const float* __restrict__ v_dst, const float* __restrict__ v_src,
    const float* __restrict__ c_dst, const float* __restrict__ c_src,
    const float* __restrict__ dnorm,
    __hip_bfloat16* __restrict__ y, float* __restrict__ gd,
    float* __restrict__ gs) {
    __shared__ short A_lds[TILE_N * 256];   // 32 KB, XOR-swizzled
    int t = threadIdx.x;
    int n0 = blockIdx.x * TILE_N;
    bool full = (n0 + TILE_N) <= N_NODES;

    // ---- stage h tile (4 passes of the 16-row pattern) ----
    #pragma unroll
    for (int rr = 0; rr < 4; ++rr) {
        int r = rr * 16 + (t >> 4), c0 = (t & 15) * 16;
        int row = n0 + r;
        if (row > N_NODES - 1) row = N_NODES - 1;   // clamp (tail block)
        const float* hp = hin + (size_t)row * IN_DIM + c0;
        float fv[16];
        *(float4*)&fv[0]  = *(const float4*)(hp + 0);
        *(float4*)&fv[4]  = *(const float4*)(hp + 4);
        *(float4*)&fv[8]  = *(const float4*)(hp + 8);
        *(float4*)&fv[12] = *(const float4*)(hp + 12);
        short sv[16];
        #pragma unroll
        for (int j = 0; j < 16; ++j) sv[j] = f2bf(fv[j]);
        int swz = (r & 7) << 3;
        int base = r * 256 + c0;
        *(bf16x8*)&A_lds[(base + 0) ^ swz] = *(bf16x8*)&sv[0];
        *(bf16x8*)&A_lds[(base + 8) ^ swz] = *(bf16x8*)&sv[8];
    }
    __syncthreads();

    int l = t & 63, w = t >> 6;
    int lr = l & 15, lg = l >> 4;
    int aswz = (lr & 7) << 3;

    f32x4 acc[4][4];   // [row-tile][col-tile]
    #pragma unroll
    for (int rt = 0; rt < 4; ++rt)
        #pragma unroll
        for (int ct = 0; ct < 4; ++ct) acc[rt][ct] = (f32x4){0.f, 0.f, 0.f, 0.f};

    #pragma unroll
    for (int ks = 0; ks < 8; ++ks) {
        bf16x8 bfrag[4], afrag[4];
        #pragma unroll
        for (int ct = 0; ct < 4; ++ct)
            bfrag[ct] = *(const bf16x8*)(W_bt + (size_t)(w * 64 + ct * 16 + lr) * 256 + ks * 32 + lg * 8);
        #pragma unroll
        for (int rt = 0; rt < 4; ++rt)
            afrag[rt] = *(bf16x8*)&A_lds[((rt * 16 + lr) * 256 + ks * 32 + lg * 8) ^ aswz];
        #pragma unroll
        for (int rt = 0; rt < 4; ++rt)
            #pragma unroll
            for (int ct = 0; ct < 4; ++ct)
                acc[rt][ct] = __builtin_amdgcn_mfma_f32_16x16x32_bf16(afrag[rt], bfrag[ct], acc[rt][ct], 0, 0, 0);
    }

    // ---- epilogue: relu(+b_in) in place, gd/gs partials ----
    int col[4];
    float vd[4], vs[4], bi[4];
    #pragma unroll
    for (int ct = 0; ct < 4; ++ct) {
        col[ct] = w * 64 + ct * 16 + lr;
        bi[ct] = b_in[col[ct]];
        vd[ct] = v_dst[col[ct]];
        vs[ct] = v_src[col[ct]];
    }
    float pd[4][4], ps[4][4];   // [rt][r]
    #pragma unroll
    for (int rt = 0; rt < 4; ++rt)
        #pragma unroll
        for (int r = 0; r < 4; ++r) { pd[rt][r] = 0.f; ps[rt][r] = 0.f; }
    #pragma unroll
    for (int rt = 0; rt < 4; ++rt)
        #pragma unroll
        for (int ct = 0; ct < 4; ++ct)
            #pragma unroll
            for (int r = 0; r < 4; ++r) {
                float v = fmaxf(acc[rt][ct][r] + bi[ct], 0.f);
                acc[rt][ct][r] = v;          // reuse as hh value
                pd[rt][r] += v * vd[ct];
                ps[rt][r] += v * vs[ct];
            }
    #pragma unroll
    for (int rt = 0; rt < 4; ++rt)
        #pragma unroll
        for (int r = 0; r < 4; ++r) {
            #pragma unroll
            for (int off = 1; off < 16; off <<= 1) {
                pd[rt][r] += __shfl_xor(pd[rt][r], off, 64);
                ps[rt][r] += __shfl_xor(ps[rt][r], off, 64);
            }
        }
    if (lr == 0) {
        float cd = c_dst[w], cs = c_src[w];
        #pragma unroll
        for (int rt = 0; rt < 4; ++rt)
            #pragma unroll
            for (int r = 0; r < 4; ++r) {
                int m = rt * 16 + lg * 4 + r;
                if (full || (n0 + m) < N_NODES) {
                    gd[(n0 + m) * HEADS + w] = pd[rt][r] + cd;
                    gs[(n0 + m) * HEADS + w] = ps[rt][r] + cs;
                }
            }
    }

    // ---- restage hh into A_lds for the y-GEMM ----
    __syncthreads();   // everyone done reading input-h tile
    #pragma unroll
    for (int rt = 0; rt < 4; ++rt)
        #pragma unroll
        for (int ct = 0; ct < 4; ++ct)
            #pragma unroll
            for (int r = 0; r < 4; ++r) {
                int m = rt * 16 + lg * 4 + r;
                int idx = m * 256 + col[ct];
                A_lds[idx ^ (((lg * 4 + r) & 7) << 3)] = f2bf(acc[rt][ct][r]);
            }
    __syncthreads();

    // ---- y-GEMM: per head w, [64 nodes x 64k] @ [64k x 64oc] ----
    f32x4 acc2[4][4];
    #pragma unroll
    for (int rt = 0; rt < 4; ++rt)
        #pragma unroll
        for (int ct = 0; ct < 4; ++ct) acc2[rt][ct] = (f32x4){0.f, 0.f, 0.f, 0.f};
    #pragma unroll
    for (int ks = 0; ks < 2; ++ks) {
        bf16x8 bfrag[4], afrag[4];
        #pragma unroll
        for (int ct = 0; ct < 4; ++ct)
            bfrag[ct] = *(const bf16x8*)(W_obt2 + (size_t)(w * 64 + ct * 16 + lr) * 64 + ks * 32 + lg * 8);
        #pragma unroll
        for (int rt = 0; rt < 4; ++rt)
            afrag[rt] = *(bf16x8*)&A_lds[((rt * 16 + lr) * 256 + w * 64 + ks * 32 + lg * 8) ^ aswz];
        #pragma unroll
        for (int rt = 0; rt < 4; ++rt)
            #pragma unroll
            for (int ct = 0; ct < 4; ++ct)
                acc2[rt][ct] = __builtin_amdgcn_mfma_f32_16x16x32_bf16(afrag[rt], bfrag[ct], acc2[rt][ct], 0, 0, 0);
    }
    #pragma unroll
    for (int rt = 0; rt < 4; ++rt)
        #pragma unroll
        for (int r = 0; r < 4; ++r) {
            int m = rt * 16 + lg * 4 + r;
            if (full || (n0 + m) < N_NODES) {
                float dnv = dnorm[n0 + m];   // fold dnorm[src] into y
                #pragma unroll
                for (int ct = 0; ct < 4; ++ct)
                    y[(size_t)(n0 + m) * HD + w * 64 + ct * 16 + lr] =
                        __float2bfloat16(acc2[rt][ct][r] * dnv);
            }
        }
}

// -------- gather agg, barrier-free, 2 nodes/wave, 16-deep MLP ----------
// lanes 0-31 -> node A, lanes 32-63 -> node B. Lane covers 8 cols (one uint4).
// y already contains dnorm[src]; alpha = g * dnorm[dst].
__global__ __launch_bounds__(256) void agg_kernel(
    const int* __restrict__ bucket_src, const int* __restrict__ cursor,
    const int* __restrict__ src, const int* __restrict__ dst,
    const int* __restrict__ ov_list, const int* __restrict__ ov_count,
    const float* __restrict__ dnorm, const float* __restrict__ b_g,
    const __hip_bfloat16* __restrict__ y, const float* __restrict__ gd,
    const float* __restrict__ gs, const float* __restrict__ b_out,
    float* __restrict__ out) {
    int t = threadIdx.x;
    int wv = t >> 6, lane = t & 63;
    int half = lane >> 5, sl = lane & 31;
    int n = blockIdx.x * 8 + wv * 2 + half;
    int head = sl >> 3;                       // flat col c = sl*8+j, head = c>>6
    int deg = cursor[n];
    if (deg > CAP) deg = CAP;
    float dn = dnorm[n];
    float gdh = gd[n * HEADS + head] + b_g[head];
    int degmax = max(deg, __shfl_xor(deg, 32, 64));   // other half's deg

    const uint4* yb = (const uint4*)y;        // row = 32 uint4
    const int* bp = bucket_src + (size_t)n * CAP;
    float a[8];
    #pragma unroll
    for (int j = 0; j < 8; ++j) a[j] = 0.f;

    for (int i = 0; i < degmax; i += 16) {
        // stage 1: 16 independent src-id broadcast loads
        int sarr[16];
        #pragma unroll
        for (int j = 0; j < 16; ++j) {
            int e = i + j;
            sarr[j] = (e < deg) ? bp[e] : -1;
        }
        // stage 2: dependent gathers, all independent -> 32 loads in flight
        float gsv[16];
        uint4 v[16];
        #pragma unroll
        for (int j = 0; j < 16; ++j) {
            int s = sarr[j] < 0 ? 0 : sarr[j];
            gsv[j] = gs[s * HEADS + head];
            v[j] = yb[(size_t)s * 32 + sl];
        }
        // stage 3: math
        #pragma unroll
        for (int j = 0; j < 16; ++j) {
            float _h = gdh + gsv[j];
            float g = _h > 0.f ? _h : -P_L * _h;
            float al = (sarr[j] < 0) ? 0.f : g * dn;
            a[0] += __uint_as_float(v[j].x << 16) * al;
            a[1] += __uint_as_float(v[j].x & 0xffff0000u) * al;
            a[2] += __uint_as_float(v[j].y << 16) * al;
            a[3] += __uint_as_float(v[j].y & 0xffff0000u) * al;
            a[4] += __uint_as_float(v[j].z << 16) * al;
            a[5] += __uint_as_float(v[j].z & 0xffff0000u) * al;
            a[6] += __uint_as_float(v[j].w << 16) * al;
            a[7] += __uint_as_float(v[j].w & 0xffff0000u) * al;
        }
    }

    // overflow edges (cnt ~always 0; uniform branch, broadcast loads)
    int cnt = *ov_count;
    if (cnt > 0) {
        if (cnt > OVCAP) cnt = OVCAP;
        for (int j = 0; j < cnt; ++j) {
            int e = ov_list[j];
            if (dst[e] == n) {
                int s = src[e];
                float _h = gdh + gs[s * HEADS + head];
                float g = _h > 0.f ? _h : -P_L * _h;
                float al = g * dn;            // y already has dnorm[s]
                uint4 vv = yb[(size_t)s * 32 + sl];
                a[0] += __uint_as_float(vv.x << 16) * al;
                a[1] += __uint_as_float(vv.x & 0xffff0000u) * al;
                a[2] += __uint_as_float(vv.y << 16) * al;
                a[3] += __uint_as_float(vv.y & 0xffff0000u) * al;
                a[4] += __uint_as_float(vv.z << 16) * al;
                a[5] += __uint_as_float(vv.z & 0xffff0000u) * al;
                a[6] += __uint_as_float(vv.w << 16) * al;
                a[7] += __uint_as_float(vv.w & 0xffff0000u) * al;
            }
        }
    }

    // reduce over heads: partners sl^8 (head bit0), sl^16 (head bit1); both <32
    #pragma unroll
    for (int j = 0; j < 8; ++j) {
        a[j] += __shfl_xor(a[j], 8, 64);
        a[j] += __shfl_xor(a[j], 16, 64);
    }
    // lanes sl<8 hold oc = sl*8+j
    if (sl < 8) {
        float4 b0 = *(const float4*)&b_out[sl * 8];
        float4 b1 = *(const float4*)&b_out[sl * 8 + 4];
        float4 o0, o1;
        o0.x = a[0] + b0.x; o0.y = a[1] + b0.y; o0.z = a[2] + b0.z; o0.w = a[3] + b0.w;
        o1.x = a[4] + b1.x; o1.y = a[5] + b1.y; o1.z = a[6] + b1.z; o1.w = a[7] + b1.w;
        *(float4*)&out[(size_t)n * OUT_DIM + sl * 8] = o0;
        *(float4*)&out[(size_t)n * OUT_DIM + sl * 8 + 4] = o1;
    }
}

extern "C" void kernel_launch(void* const* d_in, const int* in_sizes, int n_in,
                              void* d_out, int out_size, void* d_ws, size_t ws_size,
                              hipStream_t stream) {
    const float* h     = (const float*)d_in[0];
    const int*   src   = (const int*)d_in[1];
    const int*   dst   = (const int*)d_in[2];
    const float* dnorm = (const float*)d_in[3];
    const float* W_in  = (const float*)d_in[4];
    const float* b_in  = (const float*)d_in[5];
    const float* W_att = (const float*)d_in[6];
    const float* b_att = (const float*)d_in[7];
    const float* W_g   = (const float*)d_in[8];
    const float* b_g   = (const float*)d_in[9];
    const float* W_out = (const float*)d_in[10];
    const float* b_out = (const float*)d_in[11];
    float* out = (float*)d_out;

    char* ws = (char*)d_ws;
    __hip_bfloat16* y = (__hip_bfloat16*)ws;             // N*256 bf16 (25.6 MB)
    ws += (size_t)N_NODES * HD * sizeof(__hip_bfloat16);
    float* gd     = (float*)ws;  ws += (size_t)N_NODES * HEADS * sizeof(float);
    float* gs     = (float*)ws;  ws += (size_t)N_NODES * HEADS * sizeof(float);
    float* v_dst  = (float*)ws;  ws += 256 * sizeof(float);
    float* v_src  = (float*)ws;  ws += 256 * sizeof(float);
    float* c_dst  = (float*)ws;  ws += 16;
    float* c_src  = (float*)ws;  ws += 16;
    int* cursor     = (int*)ws;  ws += (size_t)N_NODES * sizeof(int);
    int* ov_count   = (int*)ws;  ws += 16;
    int* ov_list    = (int*)ws;  ws += OVCAP * sizeof(int);
    int* bucket_src = (int*)ws;  ws += (size_t)N_NODES * CAP * sizeof(int);
    short* W_bt     = (short*)ws; ws += 256 * 256 * sizeof(short);   // 128 KB
    short* W_obt2   = (short*)ws;                                    // 32 KB

    // prep covers: W_bt (256), W_obt2 (64), fold (1), cursor/ov zero (196)
    prep_kernel<<<517, 256, 0, stream>>>(W_att, b_att, W_g, W_in, W_out,
                                         W_bt, W_obt2, v_dst, v_src, c_dst, c_src,
                                         cursor, ov_count);
    fill_kernel<<<(N_EDGES + 255) / 256, 256, 0, stream>>>(src, dst, cursor, bucket_src,
                                                           ov_list, ov_count);
    node_mfma_kernel<<<(N_NODES + TILE_N - 1) / TILE_N, 256, 0, stream>>>(
        h, W_bt, W_obt2, b_in, v_dst, v_src, c_dst, c_src, dnorm, y, gd, gs);
    agg_kernel<<<N_NODES / 8, 256, 0, stream>>>(bucket_src, cursor, src, dst,
                                                ov_list, ov_count, dnorm, b_g,
                                                y, gd, gs, b_out, out);
}

// Round 18
// 156.534 us; speedup vs baseline: 1.1524x; 1.0696x over previous
//
#include <hip/hip_runtime.h>
#include <hip/hip_bf16.h>

#define N_NODES 50000
#define N_EDGES 800000
#define IN_DIM 256
#define OUT_DIM 64
#define HEADS 4
#define HD 256          // HEADS*OUT_DIM
#define P_L 0.1f
#define TILE_N 64       // nodes per block in node kernel
#define CAP 64          // per-node edge bucket capacity (expected max deg ~43)
#define OVCAP 4096      // overflow list capacity

typedef __attribute__((ext_vector_type(8))) short bf16x8;
typedef __attribute__((ext_vector_type(4))) float f32x4;

static __device__ __forceinline__ short f2bf(float f) {
    __hip_bfloat16 b = __float2bfloat16(f);
    return *(short*)&b;
}

// ---- prep: weight conversion + W_att fold + cursor/ov zeroing, one launch ----
// b<256: W_bt; b<320: W_obt2; b==320: fold; b>=321: zero cursor (+ov_count)
__global__ __launch_bounds__(256) void prep_kernel(
    const float* __restrict__ W_att, const float* __restrict__ b_att,
    const float* __restrict__ W_g,
    const float* __restrict__ W_in, const float* __restrict__ W_out,
    short* __restrict__ W_bt, short* __restrict__ W_obt2,
    float* __restrict__ v_dst, float* __restrict__ v_src,
    float* __restrict__ c_dst, float* __restrict__ c_src,
    int* __restrict__ cursor, int* __restrict__ ov_count) {
    int b = blockIdx.x, t = threadIdx.x;
    if (b < 256) {
        W_bt[t * 256 + b] = f2bf(W_in[b * 256 + t]);
    } else if (b < 320) {
        int flat = (b - 256) * 256 + t;        // [0, 16384)
        int k = flat & 63, oc = (flat >> 6) & 63, h = flat >> 12;
        W_obt2[flat] = f2bf(W_out[(h * 64 + k) * 64 + oc]);
    } else if (b == 320) {
        int h = t >> 6, dd = t & 63;
        float sd = 0.f, ss = 0.f;
        for (int e = 0; e < 64; ++e) {
            float w = W_att[h * 4096 + dd * 64 + e];
            sd += w * W_g[h * 128 + e];
            ss += w * W_g[h * 128 + 64 + e];
        }
        v_dst[t] = sd;
        v_src[t] = ss;
        if (dd == 0) {
            float cd = 0.f, cs = 0.f;
            for (int e = 0; e < 64; ++e) {
                float bb = b_att[h * 64 + e];
                cd += bb * W_g[h * 128 + e];
                cs += bb * W_g[h * 128 + 64 + e];
            }
            c_dst[h] = cd;
            c_src[h] = cs;
        }
    } else {
        int idx = (b - 321) * 256 + t;
        if (idx < N_NODES) cursor[idx] = 0;
        if (b == 321 && t == 0) *ov_count = 0;
    }
}

// ---------------- bucket fill: group SRC node ids by dst ----------------
__global__ __launch_bounds__(256) void fill_kernel(
    const int* __restrict__ src, const int* __restrict__ dst,
    int* __restrict__ cursor, int* __restrict__ bucket_src,
    int* __restrict__ ov_list, int* __restrict__ ov_count) {
    int e = blockIdx.x * 256 + threadIdx.x;
    if (e >= N_EDGES) return;
    int n = dst[e];
    int pos = atomicAdd(&cursor[n], 1);
    if (pos < CAP) {
        bucket_src[(size_t)n * CAP + pos] = src[e];
    } else {
        int oi = atomicAdd(ov_count, 1);
        if (oi < OVCAP) ov_list[oi] = e;
    }
}

// ---------------- node transform via MFMA, 512 threads, col-split waves -----
// 64 nodes/block, 8 waves: wave (ch, hd) covers cols hd*64 + ch*32 .. +31.
// Same per-block W_bt traffic as the 4-wave version; 2x occupancy.
__global__ __launch_bounds__(512) void node_mfma_kernel(
    const float* __restrict__ hin, const short* __restrict__ W_bt,
    const short* __restrict__ W_obt2, const float* __restrict__ b_in,
    const float* __restrict__ v_dst, const float* __restrict__ v_src,
    const float* __restrict__ c_dst, const float* __restrict__ c_src,
    __hip_bfloat16* __restrict__ y, float* __restrict__ gd,
    float* __restrict__ gs) {
    __shared__ short A_lds[TILE_N * 256];   // 32 KB, XOR-swizzled
    __shared__ float sm_pd[8][TILE_N];      // 2 KB: per-wave gd partials
    __shared__ float sm_ps[8][TILE_N];      // 2 KB
    int t = threadIdx.x;
    int n0 = blockIdx.x * TILE_N;
    bool full = (n0 + TILE_N) <= N_NODES;

    // ---- stage h tile: 512 threads, 2 passes of 32 rows ----
    #pragma unroll
    for (int rr = 0; rr < 2; ++rr) {
        int r = rr * 32 + (t >> 4), c0 = (t & 15) * 16;
        int row = n0 + r;
        if (row > N_NODES - 1) row = N_NODES - 1;   // clamp (tail block)
        const float* hp = hin + (size_t)row * IN_DIM + c0;
        float fv[16];
        *(float4*)&fv[0]  = *(const float4*)(hp + 0);
        *(float4*)&fv[4]  = *(const float4*)(hp + 4);
        *(float4*)&fv[8]  = *(const float4*)(hp + 8);
        *(float4*)&fv[12] = *(const float4*)(hp + 12);
        short sv[16];
        #pragma unroll
        for (int j = 0; j < 16; ++j) sv[j] = f2bf(fv[j]);
        int swz = (r & 7) << 3;
        int base = r * 256 + c0;
        *(bf16x8*)&A_lds[(base + 0) ^ swz] = *(bf16x8*)&sv[0];
        *(bf16x8*)&A_lds[(base + 8) ^ swz] = *(bf16x8*)&sv[8];
    }
    __syncthreads();

    int l = t & 63, w8 = t >> 6;          // 8 waves
    int hd = w8 & 3, ch = w8 >> 2;        // head, col-half
    int lr = l & 15, lg = l >> 4;
    int aswz = (lr & 7) << 3;

    f32x4 acc[4][2];   // [row-tile][col-tile within half]
    #pragma unroll
    for (int rt = 0; rt < 4; ++rt)
        #pragma unroll
        for (int c = 0; c < 2; ++c) acc[rt][c] = (f32x4){0.f, 0.f, 0.f, 0.f};

    int col[2];
    #pragma unroll
    for (int c = 0; c < 2; ++c) col[c] = hd * 64 + (ch * 2 + c) * 16 + lr;

    #pragma unroll
    for (int ks = 0; ks < 8; ++ks) {
        bf16x8 bfrag[2], afrag[4];
        #pragma unroll
        for (int c = 0; c < 2; ++c)
            bfrag[c] = *(const bf16x8*)(W_bt + (size_t)col[c] * 256 + ks * 32 + lg * 8);
        #pragma unroll
        for (int rt = 0; rt < 4; ++rt)
            afrag[rt] = *(bf16x8*)&A_lds[((rt * 16 + lr) * 256 + ks * 32 + lg * 8) ^ aswz];
        #pragma unroll
        for (int rt = 0; rt < 4; ++rt)
            #pragma unroll
            for (int c = 0; c < 2; ++c)
                acc[rt][c] = __builtin_amdgcn_mfma_f32_16x16x32_bf16(afrag[rt], bfrag[c], acc[rt][c], 0, 0, 0);
    }

    // ---- epilogue: relu(+b_in) in place, gd/gs partials (this wave's 2 cols)
    float vd[2], vs[2], bi[2];
    #pragma unroll
    for (int c = 0; c < 2; ++c) {
        bi[c] = b_in[col[c]];
        vd[c] = v_dst[col[c]];
        vs[c] = v_src[col[c]];
    }
    float pd[4][4], ps[4][4];   // [rt][r]
    #pragma unroll
    for (int rt = 0; rt < 4; ++rt)
        #pragma unroll
        for (int r = 0; r < 4; ++r) { pd[rt][r] = 0.f; ps[rt][r] = 0.f; }
    #pragma unroll
    for (int rt = 0; rt < 4; ++rt)
        #pragma unroll
        for (int c = 0; c < 2; ++c)
            #pragma unroll
            for (int r = 0; r < 4; ++r) {
                float v = fmaxf(acc[rt][c][r] + bi[c], 0.f);
                acc[rt][c][r] = v;          // reuse as hh value
                pd[rt][r] += v * vd[c];
                ps[rt][r] += v * vs[c];
            }
    #pragma unroll
    for (int rt = 0; rt < 4; ++rt)
        #pragma unroll
        for (int r = 0; r < 4; ++r) {
            #pragma unroll
            for (int off = 1; off < 16; off <<= 1) {
                pd[rt][r] += __shfl_xor(pd[rt][r], off, 64);
                ps[rt][r] += __shfl_xor(ps[rt][r], off, 64);
            }
        }
    if (lr == 0) {
        #pragma unroll
        for (int rt = 0; rt < 4; ++rt)
            #pragma unroll
            for (int r = 0; r < 4; ++r) {
                int m = rt * 16 + lg * 4 + r;
                sm_pd[w8][m] = pd[rt][r];
                sm_ps[w8][m] = ps[rt][r];
            }
    }

    // ---- restage hh into A_lds for the y-GEMM (this wave's 2 cols) ----
    __syncthreads();   // everyone done reading input-h tile
    #pragma unroll
    for (int rt = 0; rt < 4; ++rt)
        #pragma unroll
        for (int c = 0; c < 2; ++c)
            #pragma unroll
            for (int r = 0; r < 4; ++r) {
                int m = rt * 16 + lg * 4 + r;
                int idx = m * 256 + col[c];
                A_lds[idx ^ ((m & 7) << 3)] = f2bf(acc[rt][c][r]);
            }
    __syncthreads();

    // combine the two col-half partials -> gd/gs (threads 0..255)
    if (t < 256) {
        int m = t & 63, hh = t >> 6;
        if (full || (n0 + m) < N_NODES) {
            gd[(n0 + m) * HEADS + hh] = sm_pd[hh][m] + sm_pd[hh + 4][m] + c_dst[hh];
            gs[(n0 + m) * HEADS + hh] = sm_ps[hh][m] + sm_ps[hh + 4][m] + c_src[hh];
        }
    }

    // ---- y-GEMM: wave (ch,hd): [64 nodes x 64k of head hd] -> 2 oc-tiles ----
    f32x4 acc2[4][2];
    #pragma unroll
    for (int rt = 0; rt < 4; ++rt)
        #pragma unroll
        for (int c = 0; c < 2; ++c) acc2[rt][c] = (f32x4){0.f, 0.f, 0.f, 0.f};
    #pragma unroll
    for (int ks = 0; ks < 2; ++ks) {
        bf16x8 bfrag[2], afrag[4];
        #pragma unroll
        for (int c = 0; c < 2; ++c)
            bfrag[c] = *(const bf16x8*)(W_obt2 + (size_t)col[c] * 64 + ks * 32 + lg * 8);
        #pragma unroll
        for (int rt = 0; rt < 4; ++rt)
            afrag[rt] = *(bf16x8*)&A_lds[((rt * 16 + lr) * 256 + hd * 64 + ks * 32 + lg * 8) ^ aswz];
        #pragma unroll
        for (int rt = 0; rt < 4; ++rt)
            #pragma unroll
            for (int c = 0; c < 2; ++c)
                acc2[rt][c] = __builtin_amdgcn_mfma_f32_16x16x32_bf16(afrag[rt], bfrag[c], acc2[rt][c], 0, 0, 0);
    }
    #pragma unroll
    for (int rt = 0; rt < 4; ++rt)
        #pragma unroll
        for (int c = 0; c < 2; ++c)
            #pragma unroll
            for (int r = 0; r < 4; ++r) {
                int m = rt * 16 + lg * 4 + r;
                if (full || (n0 + m) < N_NODES)
                    y[(size_t)(n0 + m) * HD + col[c]] =
                        __float2bfloat16(acc2[rt][c][r]);
            }
}

// -------- gather agg, barrier-free, 2 nodes/wave: out[n] = b_out + sum alpha*y
// lanes 0-31 -> node A, lanes 32-63 -> node B. Lane covers 8 cols (one uint4).
__global__ __launch_bounds__(256) void agg_kernel(
    const int* __restrict__ bucket_src, const int* __restrict__ cursor,
    const int* __restrict__ src, const int* __restrict__ dst,
    const int* __restrict__ ov_list, const int* __restrict__ ov_count,
    const float* __restrict__ dnorm, const float* __restrict__ b_g,
    const __hip_bfloat16* __restrict__ y, const float* __restrict__ gd,
    const float* __restrict__ gs, const float* __restrict__ b_out,
    float* __restrict__ out) {
    int t = threadIdx.x;
    int wv = t >> 6, lane = t & 63;
    int half = lane >> 5, sl = lane & 31;
    int n = blockIdx.x * 8 + wv * 2 + half;
    int head = sl >> 3;                       // flat col c = sl*8+j, head = c>>6
    int deg = cursor[n];
    if (deg > CAP) deg = CAP;
    float dn = dnorm[n];
    float gdh = gd[n * HEADS + head] + b_g[head];
    int degmax = max(deg, __shfl_xor(deg, 32, 64));   // other half's deg

    const uint4* yb = (const uint4*)y;        // row = 32 uint4
    const int* bp = bucket_src + (size_t)n * CAP;
    float a[8];
    #pragma unroll
    for (int j = 0; j < 8; ++j) a[j] = 0.f;

    for (int i = 0; i < degmax; i += 8) {
        // stage 1: 8 independent src-id broadcast loads
        int sarr[8];
        #pragma unroll
        for (int j = 0; j < 8; ++j) {
            int e = i + j;
            sarr[j] = (e < deg) ? bp[e] : -1;
        }
        // stage 2: dependent gathers, all independent of each other
        float gsv[8], dnv[8];
        uint4 v[8];
        #pragma unroll
        for (int j = 0; j < 8; ++j) {
            int s = sarr[j] < 0 ? 0 : sarr[j];
            gsv[j] = gs[s * HEADS + head];
            dnv[j] = dnorm[s];
            v[j] = yb[(size_t)s * 32 + sl];
        }
        // stage 3: math
        #pragma unroll
        for (int j = 0; j < 8; ++j) {
            float _h = gdh + gsv[j];
            float g = _h > 0.f ? _h : -P_L * _h;
            float al = (sarr[j] < 0) ? 0.f : g * dn * dnv[j];
            a[0] += __uint_as_float(v[j].x << 16) * al;
            a[1] += __uint_as_float(v[j].x & 0xffff0000u) * al;
            a[2] += __uint_as_float(v[j].y << 16) * al;
            a[3] += __uint_as_float(v[j].y & 0xffff0000u) * al;
            a[4] += __uint_as_float(v[j].z << 16) * al;
            a[5] += __uint_as_float(v[j].z & 0xffff0000u) * al;
            a[6] += __uint_as_float(v[j].w << 16) * al;
            a[7] += __uint_as_float(v[j].w & 0xffff0000u) * al;
        }
    }

    // overflow edges (cnt ~always 0; uniform branch, broadcast loads)
    int cnt = *ov_count;
    if (cnt > 0) {
        if (cnt > OVCAP) cnt = OVCAP;
        for (int j = 0; j < cnt; ++j) {
            int e = ov_list[j];
            if (dst[e] == n) {
                int s = src[e];
                float _h = gdh + gs[s * HEADS + head];
                float g = _h > 0.f ? _h : -P_L * _h;
                float al = g * dn * dnorm[s];
                uint4 vv = yb[(size_t)s * 32 + sl];
                a[0] += __uint_as_float(vv.x << 16) * al;
                a[1] += __uint_as_float(vv.x & 0xffff0000u) * al;
                a[2] += __uint_as_float(vv.y << 16) * al;
                a[3] += __uint_as_float(vv.y & 0xffff0000u) * al;
                a[4] += __uint_as_float(vv.z << 16) * al;
                a[5] += __uint_as_float(vv.z & 0xffff0000u) * al;
                a[6] += __uint_as_float(vv.w << 16) * al;
                a[7] += __uint_as_float(vv.w & 0xffff0000u) * al;
            }
        }
    }

    // reduce over heads: partners sl^8 (head bit0), sl^16 (head bit1); both <32
    #pragma unroll
    for (int j = 0; j < 8; ++j) {
        a[j] += __shfl_xor(a[j], 8, 64);
        a[j] += __shfl_xor(a[j], 16, 64);
    }
    // lanes sl<8 hold oc = sl*8+j
    if (sl < 8) {
        float4 b0 = *(const float4*)&b_out[sl * 8];
        float4 b1 = *(const float4*)&b_out[sl * 8 + 4];
        float4 o0, o1;
        o0.x = a[0] + b0.x; o0.y = a[1] + b0.y; o0.z = a[2] + b0.z; o0.w = a[3] + b0.w;
        o1.x = a[4] + b1.x; o1.y = a[5] + b1.y; o1.z = a[6] + b1.z; o1.w = a[7] + b1.w;
        *(float4*)&out[(size_t)n * OUT_DIM + sl * 8] = o0;
        *(float4*)&out[(size_t)n * OUT_DIM + sl * 8 + 4] = o1;
    }
}

extern "C" void kernel_launch(void* const* d_in, const int* in_sizes, int n_in,
                              void* d_out, int out_size, void* d_ws, size_t ws_size,
                              hipStream_t stream) {
    const float* h     = (const float*)d_in[0];
    const int*   src   = (const int*)d_in[1];
    const int*   dst   = (const int*)d_in[2];
    const float* dnorm = (const float*)d_in[3];
    const float* W_in  = (const float*)d_in[4];
    const float* b_in  = (const float*)d_in[5];
    const float* W_att = (const float*)d_in[6];
    const float* b_att = (const float*)d_in[7];
    const float* W_g   = (const float*)d_in[8];
    const float* b_g   = (const float*)d_in[9];
    const float* W_out = (const float*)d_in[10];
    const float* b_out = (const float*)d_in[11];
    float* out = (float*)d_out;

    char* ws = (char*)d_ws;
    __hip_bfloat16* y = (__hip_bfloat16*)ws;             // N*256 bf16 (25.6 MB)
    ws += (size_t)N_NODES * HD * sizeof(__hip_bfloat16);
    float* gd     = (float*)ws;  ws += (size_t)N_NODES * HEADS * sizeof(float);
    float* gs     = (float*)ws;  ws += (size_t)N_NODES * HEADS * sizeof(float);
    float* v_dst  = (float*)ws;  ws += 256 * sizeof(float);
    float* v_src  = (float*)ws;  ws += 256 * sizeof(float);
    float* c_dst  = (float*)ws;  ws += 16;
    float* c_src  = (float*)ws;  ws += 16;
    int* cursor     = (int*)ws;  ws += (size_t)N_NODES * sizeof(int);
    int* ov_count   = (int*)ws;  ws += 16;
    int* ov_list    = (int*)ws;  ws += OVCAP * sizeof(int);
    int* bucket_src = (int*)ws;  ws += (size_t)N_NODES * CAP * sizeof(int);
    short* W_bt     = (short*)ws; ws += 256 * 256 * sizeof(short);   // 128 KB
    short* W_obt2   = (short*)ws;                                    // 32 KB

    // prep covers: W_bt (256), W_obt2 (64), fold (1), cursor/ov zero (196)
    prep_kernel<<<517, 256, 0, stream>>>(W_att, b_att, W_g, W_in, W_out,
                                         W_bt, W_obt2, v_dst, v_src, c_dst, c_src,
                                         cursor, ov_count);
    fill_kernel<<<(N_EDGES + 255) / 256, 256, 0, stream>>>(src, dst, cursor, bucket_src,
                                                           ov_list, ov_count);
    node_mfma_kernel<<<(N_NODES + TILE_N - 1) / TILE_N, 512, 0, stream>>>(
        h, W_bt, W_obt2, b_in, v_dst, v_src, c_dst, c_src, y, gd, gs);
    agg_kernel<<<N_NODES / 8, 256, 0, stream>>>(bucket_src, cursor, src, dst,
                                                ov_list, ov_count, dnorm, b_g,
                                                y, gd, gs, b_out, out);
}